// Round 8
// baseline (623.635 us; speedup 1.0000x reference)
//
#include <hip/hip_runtime.h>

typedef unsigned short u16;
typedef unsigned char u8;
typedef unsigned int u32;
typedef float f32x4 __attribute__((ext_vector_type(4)));
typedef __bf16 bf16x8 __attribute__((ext_vector_type(8)));

// ---------- bf16 helpers (RNE) ----------
__device__ __forceinline__ u16 f2bf(float f) {
    unsigned u = __float_as_uint(f);
    u += 0x7FFFu + ((u >> 16) & 1u);
    return (u16)(u >> 16);
}
__device__ __forceinline__ float b2f(u16 h) {
    return __uint_as_float(((unsigned)h) << 16);
}

// ---------- async global->LDS, 16B per lane, wave-uniform LDS base ----------
__device__ __forceinline__ void async16(const void* g, void* l) {
    __builtin_amdgcn_global_load_lds(
        (__attribute__((address_space(1))) void*)g,
        (__attribute__((address_space(3))) void*)l,
        16, 0, 0);
}

#define T_TOK 4096
#define DIM   2048

// ---------- fused: W_in cast (0..8191) + LN (8192..12287) + BC-compose (12288..12320) ----------
__global__ __launch_bounds__(256) void castln_kernel(const float* __restrict__ W_in,
                                                     u16* __restrict__ wb_in,
                                                     const float* __restrict__ x,
                                                     const float* __restrict__ g,
                                                     const float* __restrict__ b,
                                                     u16* __restrict__ xnb,
                                                     const float* __restrict__ W_B,
                                                     const float* __restrict__ W_C,
                                                     const float* __restrict__ b_in,
                                                     const float* __restrict__ b_B,
                                                     const float* __restrict__ b_C,
                                                     float* __restrict__ be) {
    __shared__ float s1[4], s2[4];
    int blk = blockIdx.x, tid = threadIdx.x;
    int wave = tid >> 6, lane = tid & 63;
    if (blk < 8192) {               // W_in cast: 2,097,152 float4s
        int i = blk * 256 + tid;
        float4 f = ((const float4*)W_in)[i];
        ushort4 u;
        u.x = f2bf(f.x); u.y = f2bf(f.y); u.z = f2bf(f.z); u.w = f2bf(f.w);
        ((ushort4*)wb_in)[i] = u;
        return;
    }
    if (blk < 12288) {              // LayerNorm
        int t = blk - 8192;
        size_t base = (size_t)t * DIM;
        int d0 = tid * 8;
        float4 v0 = *(const float4*)(x + base + d0);
        float4 v1 = *(const float4*)(x + base + d0 + 4);
        float v[8] = {v0.x, v0.y, v0.z, v0.w, v1.x, v1.y, v1.z, v1.w};
        float s = 0.f;
#pragma unroll
        for (int j = 0; j < 8; ++j) s += v[j];
#pragma unroll
        for (int o2 = 32; o2; o2 >>= 1) s += __shfl_xor(s, o2);
        if (lane == 0) s1[wave] = s;
        __syncthreads();
        float mu = (s1[0] + s1[1] + s1[2] + s1[3]) * (1.f / DIM);
        float q = 0.f;
#pragma unroll
        for (int j = 0; j < 8; ++j) { float dd = v[j] - mu; q += dd * dd; }
#pragma unroll
        for (int o2 = 32; o2; o2 >>= 1) q += __shfl_xor(q, o2);
        if (lane == 0) s2[wave] = q;
        __syncthreads();
        float var = (s2[0] + s2[1] + s2[2] + s2[3]) * (1.f / DIM);
        float rs = rsqrtf(var + 1e-5f);
        float4 g0 = *(const float4*)(g + d0), g1 = *(const float4*)(g + d0 + 4);
        float4 b0 = *(const float4*)(b + d0), b1 = *(const float4*)(b + d0 + 4);
        float gv[8] = {g0.x, g0.y, g0.z, g0.w, g1.x, g1.y, g1.z, g1.w};
        float bv[8] = {b0.x, b0.y, b0.z, b0.w, b1.x, b1.y, b1.z, b1.w};
        ushort4 r0, r1;
        u16* rp0 = (u16*)&r0; u16* rp1 = (u16*)&r1;
#pragma unroll
        for (int j = 0; j < 4; ++j) {
            rp0[j] = f2bf((v[j] - mu) * rs * gv[j] + bv[j]);
            rp1[j] = f2bf((v[j + 4] - mu) * rs * gv[j + 4] + bv[j + 4]);
        }
        *(ushort4*)(xnb + base + d0) = r0;
        *(ushort4*)(xnb + base + d0 + 4) = r1;
        return;
    }
    int cb = blk - 12288;
    if (cb < 32) {                  // W_BC_eff[n,e] = sum_d WBC[n,d]*W_in[d,e]
        int e = cb * 64 + lane;
        const float* wrow[8];
#pragma unroll
        for (int i = 0; i < 8; ++i) {
            int n = wave * 8 + i;
            wrow[i] = (n < 16) ? (W_B + (size_t)n * DIM) : (W_C + (size_t)(n - 16) * DIM);
        }
        float acc[8] = {};
        for (int d = 0; d < DIM; ++d) {
            float wv = W_in[(size_t)d * DIM + e];
#pragma unroll
            for (int i = 0; i < 8; ++i) acc[i] += wrow[i][d] * wv;
        }
#pragma unroll
        for (int i = 0; i < 8; ++i)
            wb_in[(size_t)(4096 + wave * 8 + i) * DIM + e] = f2bf(acc[i]);
        return;
    }
    // cb == 32: bias_eff[n] = sum_d WBC[n,d]*b_in[d] + bBC[n]
    int n = tid >> 3, sl = tid & 7;
    if (n < 32) {
        const float* wrow = (n < 16) ? (W_B + (size_t)n * DIM)
                                     : (W_C + (size_t)(n - 16) * DIM);
        float a = 0.f;
        for (int d = sl; d < DIM; d += 8) a += wrow[d] * b_in[d];
        a += __shfl_xor(a, 1); a += __shfl_xor(a, 2); a += __shfl_xor(a, 4);
        if (sl == 0) be[n] = a + ((n < 16) ? b_B[n] : b_C[n - 16]);
    }
}

// ---------- cast8: W_dt f32->fp8 | xsb bf16->fp8 | W_out f32->bf16 ----------
__global__ __launch_bounds__(256) void cast8_kernel(const float* __restrict__ W_dt,
                                                    u8* __restrict__ w8,
                                                    const u16* __restrict__ xsb,
                                                    u8* __restrict__ xs8,
                                                    const float* __restrict__ W_out,
                                                    u16* __restrict__ wb_out) {
    int j = blockIdx.x * 256 + threadIdx.x;
    if (j < 1048576) {              // W_dt: float4 -> 4 fp8
        float4 f = ((const float4*)W_dt)[j];
        int p = __builtin_amdgcn_cvt_pk_fp8_f32(f.x, f.y, 0, false);
        p = __builtin_amdgcn_cvt_pk_fp8_f32(f.z, f.w, p, true);
        ((u32*)w8)[j] = p;
        return;
    }
    j -= 1048576;
    if (j < 1048576) {              // xsb: 8 bf16 -> 8 fp8
        ushort4 h0 = ((const ushort4*)xsb)[2 * j];
        ushort4 h1 = ((const ushort4*)xsb)[2 * j + 1];
        int p0 = __builtin_amdgcn_cvt_pk_fp8_f32(b2f(h0.x), b2f(h0.y), 0, false);
        p0 = __builtin_amdgcn_cvt_pk_fp8_f32(b2f(h0.z), b2f(h0.w), p0, true);
        int p1 = __builtin_amdgcn_cvt_pk_fp8_f32(b2f(h1.x), b2f(h1.y), 0, false);
        p1 = __builtin_amdgcn_cvt_pk_fp8_f32(b2f(h1.z), b2f(h1.w), p1, true);
        ((u32*)xs8)[2 * j] = p0;
        ((u32*)xs8)[2 * j + 1] = p1;
        return;
    }
    j -= 1048576;
    if (j < 1048576) {              // W_out: float4 -> 4 bf16
        float4 f = ((const float4*)W_out)[j];
        ushort4 u;
        u.x = f2bf(f.x); u.y = f2bf(f.y); u.z = f2bf(f.z); u.w = f2bf(f.w);
        ((ushort4*)wb_out)[j] = u;
    }
}

// ---------- wide GEMM: 128x128 tile, BK=64, XOR-swizzled, N = 4224 (33 tiles) ----------
// Tiles 0..31: cols<2048 -> Xs, else -> Z. Tile 32: raw BC dots (cols 4096..4127).
#define WBM 128
#define WBN 128
#define WBK 64

__global__ __launch_bounds__(256) void gemm_wide(const u16* __restrict__ A,
                                                 const u16* __restrict__ W,
                                                 const float* __restrict__ bias,
                                                 u16* __restrict__ Xs,
                                                 u16* __restrict__ Z,
                                                 u16* __restrict__ dots, int K) {
    __shared__ __align__(16) u16 lAB[(WBM + WBN) * WBK];  // 32 KB
    const int tid = threadIdx.x;
    const int wave = tid >> 6, lane = tid & 63;
    const int quad = lane >> 4, l16 = lane & 15;
    const int tM = blockIdx.x * WBM;
    const int tN = blockIdx.y * WBN;
    const int wr = wave >> 1, wc = wave & 1;

    const int rowin = tid >> 3;
    const int col8 = ((tid & 7) ^ (rowin & 7)) * 8;
    const u16* gptr[8];
    u16* ldst[8];
#pragma unroll
    for (int i = 0; i < 8; ++i) {
        int trow = i * 32 + rowin;
        const u16* src = (i < 4) ? (A + (size_t)(tM + trow) * 2048)
                                 : (W + (size_t)(tN + (trow - WBM)) * 2048);
        gptr[i] = src + col8;
        ldst[i] = &lAB[(i * 32 + wave * 8) * WBK];
    }

    int a_off[2][4], b_off[2][4];
#pragma unroll
    for (int h = 0; h < 2; ++h) {
#pragma unroll
        for (int mi = 0; mi < 4; ++mi)
            a_off[h][mi] = (wr * 64 + mi * 16 + l16) * WBK +
                           (((h * 4 + quad) ^ (l16 & 7)) * 8);
#pragma unroll
        for (int ni = 0; ni < 4; ++ni)
            b_off[h][ni] = (WBM + wc * 64 + ni * 16 + l16) * WBK +
                           (((h * 4 + quad) ^ (l16 & 7)) * 8);
    }

    f32x4 acc[4][4] = {};

    for (int kt = 0; kt < K; kt += WBK) {
#pragma unroll
        for (int i = 0; i < 8; ++i) async16(gptr[i] + kt, ldst[i]);
        __syncthreads();
#pragma unroll
        for (int h = 0; h < 2; ++h) {
            bf16x8 af[4], bfr[4];
#pragma unroll
            for (int i = 0; i < 4; ++i) af[i] = *(const bf16x8*)&lAB[a_off[h][i]];
#pragma unroll
            for (int i = 0; i < 4; ++i) bfr[i] = *(const bf16x8*)&lAB[b_off[h][i]];
#pragma unroll
            for (int mi = 0; mi < 4; ++mi)
#pragma unroll
                for (int ni = 0; ni < 4; ++ni)
                    acc[mi][ni] = __builtin_amdgcn_mfma_f32_16x16x32_bf16(
                        af[mi], bfr[ni], acc[mi][ni], 0, 0, 0);
        }
        __syncthreads();
    }

    if (tN >= 4096) {               // BC-dots tile: raw, no bias
        if (wc == 0) {
#pragma unroll
            for (int mi = 0; mi < 4; ++mi)
#pragma unroll
                for (int ni = 0; ni < 2; ++ni) {
                    int nc = ni * 16 + l16;   // 0..31
#pragma unroll
                    for (int r = 0; r < 4; ++r) {
                        int row = tM + wr * 64 + mi * 16 + quad * 4 + r;
                        dots[(size_t)row * 32 + nc] = f2bf(acc[mi][ni][r]);
                    }
                }
        }
        return;
    }
    const bool isb_z = (tN >= 2048);
    u16* dst = isb_z ? Z : Xs;
#pragma unroll
    for (int mi = 0; mi < 4; ++mi) {
#pragma unroll
        for (int ni = 0; ni < 4; ++ni) {
            int col = tN + wc * 64 + ni * 16 + l16;
            float bv = bias[col];
            int ocol = isb_z ? (col - 2048) : col;
#pragma unroll
            for (int r = 0; r < 4; ++r) {
                int row = tM + wr * 64 + mi * 16 + quad * 4 + r;
                dst[(size_t)row * 2048 + ocol] = f2bf(acc[mi][ni][r] + bv);
            }
        }
    }
}

// ---------- dt GEMM, fp8: BM=128, BN=64, BK=128 (bytes), 16x16x32_fp8_fp8 ----------
// Same 24 KB LDS / 6-DMA-round / 16B-chunk-XOR-swizzle geometry as the proven
// bf16 narrow kernel (rows are 128 B either way); half the K-iterations.
// Epilogue: dt = min(softplus(v + bias), 1) stored as fp8 e4m3.
__global__ __launch_bounds__(256) void gemm_dt8(const u8* __restrict__ A,
                                                const u8* __restrict__ W,
                                                const float* __restrict__ bias,
                                                u8* __restrict__ dt8) {
    __shared__ __align__(16) u8 lAB[192 * 128];   // 24 KB
    const int tid = threadIdx.x;
    const int wave = tid >> 6, lane = tid & 63;
    const int quad = lane >> 4, l16 = lane & 15;
    const int tM = blockIdx.x * 128;
    const int tN = blockIdx.y * 64;
    const int wr = wave >> 1, wc = wave & 1;

    const int rowin = tid >> 3;                       // 0..31
    const int col16 = ((tid & 7) ^ (rowin & 7)) * 16; // swizzled 16B source chunk
    const u8* gptr[6];
    u8* ldst[6];
#pragma unroll
    for (int i = 0; i < 6; ++i) {
        int trow = i * 32 + rowin;
        const u8* src = (i < 4) ? (A + (size_t)(tM + trow) * 2048)
                                : (W + (size_t)(tN + (trow - 128)) * 2048);
        gptr[i] = src + col16;
        ldst[i] = &lAB[(i * 32 + wave * 8) * 128];
    }

    // frag byte offset within row for k-quarter h: h*32 + quad*8
    // 16B chunk c = 2h + (quad>>1), swizzled slot = c ^ (row&7), + (quad&1)*8
    int a_off[4][4], b_off[4][2];
#pragma unroll
    for (int h = 0; h < 4; ++h) {
        int c = 2 * h + (quad >> 1);
        int half = (quad & 1) * 8;
#pragma unroll
        for (int mi = 0; mi < 4; ++mi) {
            int row = wr * 64 + mi * 16 + l16;
            a_off[h][mi] = row * 128 + ((c ^ (row & 7)) << 4) + half;
        }
#pragma unroll
        for (int ni = 0; ni < 2; ++ni) {
            int row = 128 + wc * 32 + ni * 16 + l16;
            b_off[h][ni] = row * 128 + ((c ^ (row & 7)) << 4) + half;
        }
    }

    f32x4 acc[4][2] = {};

    for (int kt = 0; kt < 2048; kt += 128) {
#pragma unroll
        for (int i = 0; i < 6; ++i) async16(gptr[i] + kt, ldst[i]);
        __syncthreads();
#pragma unroll
        for (int h = 0; h < 4; ++h) {
            long long af[4], bf[2];
#pragma unroll
            for (int mi = 0; mi < 4; ++mi) af[mi] = *(const long long*)&lAB[a_off[h][mi]];
#pragma unroll
            for (int ni = 0; ni < 2; ++ni) bf[ni] = *(const long long*)&lAB[b_off[h][ni]];
#pragma unroll
            for (int mi = 0; mi < 4; ++mi)
#pragma unroll
                for (int ni = 0; ni < 2; ++ni)
                    acc[mi][ni] = __builtin_amdgcn_mfma_f32_16x16x32_fp8_fp8(
                        af[mi], bf[ni], acc[mi][ni], 0, 0, 0);
        }
        __syncthreads();
    }

#pragma unroll
    for (int mi = 0; mi < 4; ++mi) {
#pragma unroll
        for (int ni = 0; ni < 2; ++ni) {
            int col = tN + wc * 32 + ni * 16 + l16;
            float bv = bias[col];
#pragma unroll
            for (int r = 0; r < 4; ++r) {
                int row = tM + wr * 64 + mi * 16 + quad * 4 + r;
                float v = acc[mi][ni][r] + bv;
                float sp = (v > 20.f) ? v : log1pf(__expf(v));
                sp = fminf(sp, 1.0f);
                int p = __builtin_amdgcn_cvt_pk_fp8_f32(sp, sp, 0, false);
                dt8[(size_t)row * 2048 + col] = (u8)(p & 0xFF);
            }
        }
    }
}

// ---------- out GEMM (bf16 narrow, round-6/7 proven): BM=128, BN=64, BK=64 ----------
__global__ __launch_bounds__(256) void gemm_out(const u16* __restrict__ A,
                                                const u16* __restrict__ W,
                                                const float* __restrict__ bias,
                                                const float* __restrict__ resid,
                                                float* __restrict__ C) {
    __shared__ __align__(16) u16 lAB[192 * 64];  // 24 KB
    const int tid = threadIdx.x;
    const int wave = tid >> 6, lane = tid & 63;
    const int quad = lane >> 4, l16 = lane & 15;
    const int tM = blockIdx.x * 128;
    const int tN = blockIdx.y * 64;
    const int wr = wave >> 1, wc = wave & 1;

    const int rowin = tid >> 3;
    const int col8 = ((tid & 7) ^ (rowin & 7)) * 8;
    const u16* gptr[6];
    u16* ldst[6];
#pragma unroll
    for (int i = 0; i < 6; ++i) {
        int trow = i * 32 + rowin;
        const u16* src = (i < 4) ? (A + (size_t)(tM + trow) * 2048)
                                 : (W + (size_t)(tN + (trow - 128)) * 2048);
        gptr[i] = src + col8;
        ldst[i] = &lAB[(i * 32 + wave * 8) * 64];
    }

    int a_off[2][4], b_off[2][2];
#pragma unroll
    for (int h = 0; h < 2; ++h) {
#pragma unroll
        for (int mi = 0; mi < 4; ++mi)
            a_off[h][mi] = (wr * 64 + mi * 16 + l16) * 64 +
                           (((h * 4 + quad) ^ (l16 & 7)) * 8);
#pragma unroll
        for (int ni = 0; ni < 2; ++ni)
            b_off[h][ni] = (128 + wc * 32 + ni * 16 + l16) * 64 +
                           (((h * 4 + quad) ^ (l16 & 7)) * 8);
    }

    f32x4 acc[4][2] = {};

    for (int kt = 0; kt < 2048; kt += 64) {
#pragma unroll
        for (int i = 0; i < 6; ++i) async16(gptr[i] + kt, ldst[i]);
        __syncthreads();
        bf16x8 af[2][4], bfr[2][2];
#pragma unroll
        for (int h = 0; h < 2; ++h) {
#pragma unroll
            for (int mi = 0; mi < 4; ++mi) af[h][mi] = *(const bf16x8*)&lAB[a_off[h][mi]];
#pragma unroll
            for (int ni = 0; ni < 2; ++ni) bfr[h][ni] = *(const bf16x8*)&lAB[b_off[h][ni]];
        }
#pragma unroll
        for (int h = 0; h < 2; ++h)
#pragma unroll
            for (int mi = 0; mi < 4; ++mi)
#pragma unroll
                for (int ni = 0; ni < 2; ++ni)
                    acc[mi][ni] = __builtin_amdgcn_mfma_f32_16x16x32_bf16(
                        af[h][mi], bfr[h][ni], acc[mi][ni], 0, 0, 0);
        __syncthreads();
    }

#pragma unroll
    for (int mi = 0; mi < 4; ++mi) {
#pragma unroll
        for (int ni = 0; ni < 2; ++ni) {
            int col = tN + wc * 32 + ni * 16 + l16;
            float bv = bias[col];
#pragma unroll
            for (int r = 0; r < 4; ++r) {
                int row = tM + wr * 64 + mi * 16 + quad * 4 + r;
                size_t idx = (size_t)row * 2048 + col;
                C[idx] = acc[mi][ni][r] + bv + resid[idx];
            }
        }
    }
}

// ---------- fused P + SSM + gate (fp8 dt, composed-bias P) ----------
__global__ __launch_bounds__(256) void ssm_gate_kernel(const u8* __restrict__ dt8,
                                                       const u16* __restrict__ xsb,
                                                       const u16* __restrict__ zb,
                                                       const float* __restrict__ A,
                                                       const u16* __restrict__ dots,
                                                       const float* __restrict__ be,
                                                       u16* __restrict__ gated) {
    __shared__ float Pl[16];
    int t = blockIdx.x, tid = threadIdx.x;
    if (tid < 16) {
        float Bv = b2f(dots[(size_t)t * 32 + tid]) + be[tid];
        float Cv = b2f(dots[(size_t)t * 32 + 16 + tid]) + be[16 + tid];
        Pl[tid] = Bv * Cv;
    }
    __syncthreads();
    size_t dbase = (size_t)t * DIM;
    int d0 = tid * 8;
    unsigned long long dl = *(const unsigned long long*)(dt8 + dbase + d0);
    unsigned dlo = (unsigned)dl, dhi = (unsigned)(dl >> 32);
    ushort4 xsh[2], zh[2];
    xsh[0] = *(const ushort4*)(xsb + dbase + d0);
    xsh[1] = *(const ushort4*)(xsb + dbase + d0 + 4);
    zh[0]  = *(const ushort4*)(zb + dbase + d0);
    zh[1]  = *(const ushort4*)(zb + dbase + d0 + 4);
    float dtv[8], xsv[8], zv[8];
    dtv[0] = __builtin_amdgcn_cvt_f32_fp8(dlo, 0);
    dtv[1] = __builtin_amdgcn_cvt_f32_fp8(dlo, 1);
    dtv[2] = __builtin_amdgcn_cvt_f32_fp8(dlo, 2);
    dtv[3] = __builtin_amdgcn_cvt_f32_fp8(dlo, 3);
    dtv[4] = __builtin_amdgcn_cvt_f32_fp8(dhi, 0);
    dtv[5] = __builtin_amdgcn_cvt_f32_fp8(dhi, 1);
    dtv[6] = __builtin_amdgcn_cvt_f32_fp8(dhi, 2);
    dtv[7] = __builtin_amdgcn_cvt_f32_fp8(dhi, 3);
#pragma unroll
    for (int h = 0; h < 2; ++h) {
        const u16* xp = (const u16*)&xsh[h];
        const u16* zp = (const u16*)&zh[h];
#pragma unroll
        for (int j = 0; j < 4; ++j) {
            xsv[h * 4 + j] = b2f(xp[j]);
            zv[h * 4 + j]  = b2f(zp[j]);
        }
    }
    float s[8] = {};
#pragma unroll
    for (int n = 0; n < 16; ++n) {
        float4 a0 = *(const float4*)(A + n * DIM + d0);
        float4 a1 = *(const float4*)(A + n * DIM + d0 + 4);
        float pn = Pl[n];
        float av[8] = {a0.x, a0.y, a0.z, a0.w, a1.x, a1.y, a1.z, a1.w};
#pragma unroll
        for (int j = 0; j < 8; ++j) s[j] += pn * __expf(av[j] * dtv[j]);
    }
    ushort4 r0, r1;
    u16* rp0 = (u16*)&r0; u16* rp1 = (u16*)&r1;
#pragma unroll
    for (int j = 0; j < 8; ++j) {
        float y = s[j] * xsv[j];
        float sz = zv[j] * (1.0f / (1.0f + __expf(-zv[j])));
        u16 hv = f2bf(y * sz);
        if (j < 4) rp0[j] = hv; else rp1[j - 4] = hv;
    }
    *(ushort4*)(gated + dbase + d0) = r0;
    *(ushort4*)(gated + dbase + d0 + 4) = r1;
}

// ---------- launch ----------
// ws layout (75.9 MB peak, < proven 84.15):
//   A0 [0, 16.91M):        wb_in bf16 4128x2048 (rows 4096..4127 = W_BC_eff)
//                          -> w8_dt fp8 2048x2048 (cast8) -> gated bf16 (ssm_gate)
//   B0 [16.91M, 33.69M):   xnb bf16 -> wb_out bf16 @B0 + xs8 fp8 @B0+8.39M
//   C0 [33.69M, 50.46M):   xsb bf16
//   D0 [50.46M, 67.24M):   zb bf16
//   E0 [67.24M, 75.63M):   dt8 fp8
//   F0 [75.63M, 75.89M):   dots bf16 (T x 32)
//   G0 [75.89M, +128):     bias_eff fp32[32]
extern "C" void kernel_launch(void* const* d_in, const int* in_sizes, int n_in,
                              void* d_out, int out_size, void* d_ws, size_t ws_size,
                              hipStream_t stream) {
    const float* x      = (const float*)d_in[0];
    const float* ln_g   = (const float*)d_in[1];
    const float* ln_b   = (const float*)d_in[2];
    const float* W_in   = (const float*)d_in[3];
    const float* b_in   = (const float*)d_in[4];
    const float* stateA = (const float*)d_in[5];
    const float* W_B    = (const float*)d_in[6];
    const float* b_B    = (const float*)d_in[7];
    const float* W_C    = (const float*)d_in[8];
    const float* b_C    = (const float*)d_in[9];
    const float* W_dt   = (const float*)d_in[10];
    const float* b_dt   = (const float*)d_in[11];
    const float* W_out  = (const float*)d_in[12];
    const float* b_out  = (const float*)d_in[13];

    char* ws = (char*)d_ws;
    u16*   wb_in  = (u16*)(ws);                       // A0
    u8*    w8_dt  = (u8*)(ws);                        // A0 reuse
    u16*   gated  = (u16*)(ws);                       // A0 reuse
    u16*   xnb    = (u16*)(ws + 16908288);            // B0
    u16*   wb_out = (u16*)(ws + 16908288);            // B0 reuse
    u8*    xs8    = (u8*)(ws + 16908288 + 8388608);   // B0 reuse (upper half)
    u16*   xsb    = (u16*)(ws + 33685504);            // C0
    u16*   zb     = (u16*)(ws + 50462720);            // D0
    u8*    dt8    = (u8*)(ws + 67239936);             // E0
    u16*   dotsb  = (u16*)(ws + 75628544);            // F0
    float* be     = (float*)(ws + 75890688);          // G0

    // 1. W_in cast + LN + BC-compose + bias_eff
    castln_kernel<<<12321, 256, 0, stream>>>(W_in, wb_in, x, ln_g, ln_b, xnb,
                                             W_B, W_C, b_in, b_B, b_C, be);
    // 2. [xs | z | dots] = xn @ [W_in; W_BC_eff]^T   (N = 4224, 33 tiles)
    gemm_wide<<<dim3(32, 33), 256, 0, stream>>>(xnb, wb_in, b_in, xsb, zb,
                                                dotsb, 2048);
    // 3. casts: W_dt->fp8, xsb->fp8, W_out->bf16 (wb_in/xnb dead)
    cast8_kernel<<<12288, 256, 0, stream>>>(W_dt, w8_dt, xsb, xs8, W_out, wb_out);
    // 4. dt = min(softplus(xs8 @ w8^T + b_dt), 1) -> fp8   (fp8 GEMM, BK=128)
    gemm_dt8<<<dim3(32, 32), 256, 0, stream>>>(xs8, w8_dt, b_dt, dt8);
    // 5. fused P + SSM + gate (gated overwrites A0; w8_dt dead)
    ssm_gate_kernel<<<T_TOK, 256, 0, stream>>>(dt8, xsb, zb, stateA, dotsb,
                                               be, gated);
    // 6. out = gated @ W_out^T + b_out + x
    gemm_out<<<dim3(32, 32), 256, 0, stream>>>(gated, wb_out, b_out, x,
                                               (float*)d_out);
}

// Round 9
// 400.760 us; speedup vs baseline: 1.5561x; 1.5561x over previous
//
#include <hip/hip_runtime.h>

typedef unsigned short u16;
typedef float f32x4 __attribute__((ext_vector_type(4)));
typedef __bf16 bf16x8 __attribute__((ext_vector_type(8)));

// ---------- bf16 helpers (RNE) ----------
__device__ __forceinline__ u16 f2bf(float f) {
    unsigned u = __float_as_uint(f);
    u += 0x7FFFu + ((u >> 16) & 1u);
    return (u16)(u >> 16);
}
__device__ __forceinline__ float b2f(u16 h) {
    return __uint_as_float(((unsigned)h) << 16);
}

// ---------- async global->LDS, 16B per lane, wave-uniform LDS base ----------
__device__ __forceinline__ void async16(const u16* g, u16* l) {
    __builtin_amdgcn_global_load_lds(
        (__attribute__((address_space(1))) void*)(u16*)g,
        (__attribute__((address_space(3))) void*)l,
        16, 0, 0);
}

#define T_TOK 4096
#define DIM   2048

__device__ __forceinline__ void cast4f(const float* __restrict__ s,
                                       u16* __restrict__ d, int j) {
    float4 f = ((const float4*)s)[j];
    ushort4 u;
    u.x = f2bf(f.x); u.y = f2bf(f.y); u.z = f2bf(f.z); u.w = f2bf(f.w);
    ((ushort4*)d)[j] = u;
}

__device__ __forceinline__ void ln_token(int t, int tid,
                                         const float* __restrict__ x,
                                         const float* __restrict__ g,
                                         const float* __restrict__ b,
                                         u16* __restrict__ o,
                                         float* s1, float* s2) {
    int wave = tid >> 6, lane = tid & 63;
    size_t base = (size_t)t * DIM;
    int d0 = tid * 8;
    float4 v0 = *(const float4*)(x + base + d0);
    float4 v1 = *(const float4*)(x + base + d0 + 4);
    float v[8] = {v0.x, v0.y, v0.z, v0.w, v1.x, v1.y, v1.z, v1.w};
    float s = 0.f;
#pragma unroll
    for (int j = 0; j < 8; ++j) s += v[j];
#pragma unroll
    for (int o2 = 32; o2; o2 >>= 1) s += __shfl_xor(s, o2);
    if (lane == 0) s1[wave] = s;
    __syncthreads();
    float mu = (s1[0] + s1[1] + s1[2] + s1[3]) * (1.f / DIM);
    float q = 0.f;
#pragma unroll
    for (int j = 0; j < 8; ++j) { float dd = v[j] - mu; q += dd * dd; }
#pragma unroll
    for (int o2 = 32; o2; o2 >>= 1) q += __shfl_xor(q, o2);
    if (lane == 0) s2[wave] = q;
    __syncthreads();
    float var = (s2[0] + s2[1] + s2[2] + s2[3]) * (1.f / DIM);
    float rs = rsqrtf(var + 1e-5f);
    float4 g0 = *(const float4*)(g + d0), g1 = *(const float4*)(g + d0 + 4);
    float4 b0 = *(const float4*)(b + d0), b1 = *(const float4*)(b + d0 + 4);
    float gv[8] = {g0.x, g0.y, g0.z, g0.w, g1.x, g1.y, g1.z, g1.w};
    float bv[8] = {b0.x, b0.y, b0.z, b0.w, b1.x, b1.y, b1.z, b1.w};
    ushort4 r0, r1;
    u16* rp0 = (u16*)&r0; u16* rp1 = (u16*)&r1;
#pragma unroll
    for (int j = 0; j < 4; ++j) {
        rp0[j] = f2bf((v[j] - mu) * rs * gv[j] + bv[j]);
        rp1[j] = f2bf((v[j + 4] - mu) * rs * gv[j + 4] + bv[j + 4]);
    }
    *(ushort4*)(o + base + d0) = r0;
    *(ushort4*)(o + base + d0 + 4) = r1;
}

// ---------- fallback kernel A: W_in cast (0..8191) + LN (8192..12287) ----------
__global__ __launch_bounds__(256) void castln_kernel(const float* __restrict__ W_in,
                                                     u16* __restrict__ wb_in,
                                                     const float* __restrict__ x,
                                                     const float* __restrict__ g,
                                                     const float* __restrict__ b,
                                                     u16* __restrict__ xnb) {
    __shared__ float s1[4], s2[4];
    int blk = blockIdx.x, tid = threadIdx.x;
    if (blk < 8192) { cast4f(W_in, wb_in, blk * 256 + tid); return; }
    ln_token(blk - 8192, tid, x, g, b, xnb, s1, s2);
}

// ---------- fallback kernel B: 4-range weight cast ----------
__global__ __launch_bounds__(256) void cast4_kernel(const float* __restrict__ s0, u16* __restrict__ d0, int n0,
                                                    const float* __restrict__ s1, u16* __restrict__ d1, int n1,
                                                    const float* __restrict__ s2, u16* __restrict__ d2, int n2,
                                                    const float* __restrict__ s3, u16* __restrict__ d3, int n3) {
    int j = blockIdx.x * 256 + threadIdx.x;
    const float* s; u16* d;
    if (j < n0) { s = s0; d = d0; }
    else {
        j -= n0;
        if (j < n1) { s = s1; d = d1; }
        else {
            j -= n1;
            if (j < n2) { s = s2; d = d2; }
            else { j -= n2; if (j >= n3) return; s = s3; d = d3; }
        }
    }
    cast4f(s, d, j);
}

// ---------- primary kernel: ALL casts + LN in one launch (20544 blocks) ----------
// blocks [0,8192): W_in cast; [8192,12288): LN; [12288,16384): W_dt cast;
// [16384,16448): W_B/W_C -> wb_dt rows 2048..2079; [16448,20544): W_out cast.
// All segments are pure elementwise/per-token parallel work — no serial tails.
__global__ __launch_bounds__(256) void castall_kernel(const float* __restrict__ W_in,
                                                      u16* __restrict__ wb_in,
                                                      const float* __restrict__ x,
                                                      const float* __restrict__ g,
                                                      const float* __restrict__ b,
                                                      u16* __restrict__ xnb,
                                                      const float* __restrict__ W_dt,
                                                      const float* __restrict__ W_B,
                                                      const float* __restrict__ W_C,
                                                      u16* __restrict__ wb_dt,
                                                      const float* __restrict__ W_out,
                                                      u16* __restrict__ wb_out) {
    __shared__ float s1[4], s2[4];
    int blk = blockIdx.x, tid = threadIdx.x;
    if (blk < 8192) { cast4f(W_in, wb_in, blk * 256 + tid); return; }
    if (blk < 12288) { ln_token(blk - 8192, tid, x, g, b, xnb, s1, s2); return; }
    if (blk < 16384) { cast4f(W_dt, wb_dt, (blk - 12288) * 256 + tid); return; }
    if (blk < 16448) {
        int j = (blk - 16384) * 256 + tid;
        if (j < 8192) cast4f(W_B, wb_dt + (size_t)2048 * 2048, j);
        else          cast4f(W_C, wb_dt + (size_t)2064 * 2048, j - 8192);
        return;
    }
    cast4f(W_out, wb_out, (blk - 16448) * 256 + tid);
}

// ---------- wide GEMM: 128x128 tile, BK=64, XOR-swizzled LDS (round-7 proven) ----------
#define WBM 128
#define WBN 128
#define WBK 64

__global__ __launch_bounds__(256) void gemm_wide(const u16* __restrict__ A,
                                                 const u16* __restrict__ W,
                                                 const float* __restrict__ bias,
                                                 u16* __restrict__ Xs,
                                                 u16* __restrict__ Z, int K) {
    __shared__ __align__(16) u16 lAB[(WBM + WBN) * WBK];  // 32 KB
    const int tid = threadIdx.x;
    const int wave = tid >> 6, lane = tid & 63;
    const int quad = lane >> 4, l16 = lane & 15;
    const int tM = blockIdx.x * WBM;
    const int tN = blockIdx.y * WBN;
    const int wr = wave >> 1, wc = wave & 1;

    const int rowin = tid >> 3;
    const int col8 = ((tid & 7) ^ (rowin & 7)) * 8;
    const u16* gptr[8];
    u16* ldst[8];
#pragma unroll
    for (int i = 0; i < 8; ++i) {
        int trow = i * 32 + rowin;
        const u16* src = (i < 4) ? (A + (size_t)(tM + trow) * 2048)
                                 : (W + (size_t)(tN + (trow - WBM)) * 2048);
        gptr[i] = src + col8;
        ldst[i] = &lAB[(i * 32 + wave * 8) * WBK];
    }

    int a_off[2][4], b_off[2][4];
#pragma unroll
    for (int h = 0; h < 2; ++h) {
#pragma unroll
        for (int mi = 0; mi < 4; ++mi)
            a_off[h][mi] = (wr * 64 + mi * 16 + l16) * WBK +
                           (((h * 4 + quad) ^ (l16 & 7)) * 8);
#pragma unroll
        for (int ni = 0; ni < 4; ++ni)
            b_off[h][ni] = (WBM + wc * 64 + ni * 16 + l16) * WBK +
                           (((h * 4 + quad) ^ (l16 & 7)) * 8);
    }

    f32x4 acc[4][4] = {};

    for (int kt = 0; kt < K; kt += WBK) {
#pragma unroll
        for (int i = 0; i < 8; ++i) async16(gptr[i] + kt, ldst[i]);
        __syncthreads();
#pragma unroll
        for (int h = 0; h < 2; ++h) {
            bf16x8 af[4], bfr[4];
#pragma unroll
            for (int i = 0; i < 4; ++i) af[i] = *(const bf16x8*)&lAB[a_off[h][i]];
#pragma unroll
            for (int i = 0; i < 4; ++i) bfr[i] = *(const bf16x8*)&lAB[b_off[h][i]];
#pragma unroll
            for (int mi = 0; mi < 4; ++mi)
#pragma unroll
                for (int ni = 0; ni < 4; ++ni)
                    acc[mi][ni] = __builtin_amdgcn_mfma_f32_16x16x32_bf16(
                        af[mi], bfr[ni], acc[mi][ni], 0, 0, 0);
        }
        __syncthreads();
    }

    const bool isb_z = (tN >= 2048);
    u16* dst = isb_z ? Z : Xs;
#pragma unroll
    for (int mi = 0; mi < 4; ++mi) {
#pragma unroll
        for (int ni = 0; ni < 4; ++ni) {
            int col = tN + wc * 64 + ni * 16 + l16;
            float bv = bias[col];
            int ocol = isb_z ? (col - 2048) : col;
#pragma unroll
            for (int r = 0; r < 4; ++r) {
                int row = tM + wr * 64 + mi * 16 + quad * 4 + r;
                dst[(size_t)row * 2048 + ocol] = f2bf(acc[mi][ni][r] + bv);
            }
        }
    }
}

// ---------- narrow GEMM: BM=128, BN=64, BK=64, XOR-swizzled (round-6/7 proven) ----------
// EPI 1 = dt: col<2048 -> min(softplus(v),1) bf16; 2048<=col<2080 -> raw dots bf16.
// EPI 2 = out: fp32 v + resid.
#define NBM 128
#define NBN 64
#define NBK 64

template <int EPI>
__global__ __launch_bounds__(256) void gemm_nw(const u16* __restrict__ A, int lda,
                                               const u16* __restrict__ W, int ldw,
                                               const float* __restrict__ bias,
                                               const float* __restrict__ resid,
                                               void* __restrict__ C, int ldc, int K,
                                               u16* __restrict__ dots) {
    __shared__ __align__(16) u16 lAB[(NBM + NBN) * NBK];  // 24 KB
    const int tid = threadIdx.x;
    const int wave = tid >> 6, lane = tid & 63;
    const int quad = lane >> 4, l16 = lane & 15;
    const int tM = blockIdx.x * NBM;
    const int tN = blockIdx.y * NBN;
    const int wr = wave >> 1, wc = wave & 1;

    const int rowin = tid >> 3;
    const int col8 = ((tid & 7) ^ (rowin & 7)) * 8;
    const u16* gptr[6];
    u16* ldst[6];
#pragma unroll
    for (int i = 0; i < 6; ++i) {
        int trow = i * 32 + rowin;
        const u16* src = (i < 4) ? (A + (size_t)(tM + trow) * lda)
                                 : (W + (size_t)(tN + (trow - NBM)) * ldw);
        gptr[i] = src + col8;
        ldst[i] = &lAB[(i * 32 + wave * 8) * NBK];
    }

    int a_off[2][4], b_off[2][2];
#pragma unroll
    for (int h = 0; h < 2; ++h) {
#pragma unroll
        for (int mi = 0; mi < 4; ++mi)
            a_off[h][mi] = (wr * 64 + mi * 16 + l16) * NBK +
                           (((h * 4 + quad) ^ (l16 & 7)) * 8);
#pragma unroll
        for (int ni = 0; ni < 2; ++ni)
            b_off[h][ni] = (NBM + wc * 32 + ni * 16 + l16) * NBK +
                           (((h * 4 + quad) ^ (l16 & 7)) * 8);
    }

    f32x4 acc[4][2] = {};

    for (int kt = 0; kt < K; kt += NBK) {
#pragma unroll
        for (int i = 0; i < 6; ++i) async16(gptr[i] + kt, ldst[i]);
        __syncthreads();
        bf16x8 af[2][4], bfr[2][2];
#pragma unroll
        for (int h = 0; h < 2; ++h) {
#pragma unroll
            for (int mi = 0; mi < 4; ++mi) af[h][mi] = *(const bf16x8*)&lAB[a_off[h][mi]];
#pragma unroll
            for (int ni = 0; ni < 2; ++ni) bfr[h][ni] = *(const bf16x8*)&lAB[b_off[h][ni]];
        }
#pragma unroll
        for (int h = 0; h < 2; ++h)
#pragma unroll
            for (int mi = 0; mi < 4; ++mi)
#pragma unroll
                for (int ni = 0; ni < 2; ++ni)
                    acc[mi][ni] = __builtin_amdgcn_mfma_f32_16x16x32_bf16(
                        af[h][mi], bfr[h][ni], acc[mi][ni], 0, 0, 0);
        __syncthreads();
    }

#pragma unroll
    for (int mi = 0; mi < 4; ++mi) {
#pragma unroll
        for (int ni = 0; ni < 2; ++ni) {
            int col = tN + wc * 32 + ni * 16 + l16;
            float bv = (EPI == 1 && col >= 2048) ? 0.f : bias[col];
#pragma unroll
            for (int r = 0; r < 4; ++r) {
                int row = tM + wr * 64 + mi * 16 + quad * 4 + r;
                float v = acc[mi][ni][r] + bv;
                if constexpr (EPI == 1) {
                    if (col < 2048) {
                        float sp = (v > 20.f) ? v : log1pf(__expf(v));
                        ((u16*)C)[(size_t)row * ldc + col] = f2bf(fminf(sp, 1.0f));
                    } else if (col < 2080) {
                        dots[(size_t)row * 32 + (col - 2048)] = f2bf(v);
                    }
                } else {
                    size_t idx = (size_t)row * ldc + col;
                    ((float*)C)[idx] = v + resid[idx];
                }
            }
        }
    }
}

// ---------- fused P + SSM + gate (round-7 proven) ----------
__global__ __launch_bounds__(256) void ssm_gate_kernel(const u16* __restrict__ dtb,
                                                       const u16* __restrict__ xsb,
                                                       const u16* __restrict__ zb,
                                                       const float* __restrict__ A,
                                                       const u16* __restrict__ dots,
                                                       const float* __restrict__ bB,
                                                       const float* __restrict__ bC,
                                                       u16* __restrict__ gated) {
    __shared__ float Pl[16];
    int t = blockIdx.x, tid = threadIdx.x;
    if (tid < 16) {
        float Bv = b2f(dots[(size_t)t * 32 + tid]) + bB[tid];
        float Cv = b2f(dots[(size_t)t * 32 + 16 + tid]) + bC[tid];
        Pl[tid] = Bv * Cv;
    }
    __syncthreads();
    size_t dbase = (size_t)t * DIM;
    int d0 = tid * 8;
    ushort4 dth[2], xsh[2], zh[2];
    dth[0] = *(const ushort4*)(dtb + dbase + d0);
    dth[1] = *(const ushort4*)(dtb + dbase + d0 + 4);
    xsh[0] = *(const ushort4*)(xsb + dbase + d0);
    xsh[1] = *(const ushort4*)(xsb + dbase + d0 + 4);
    zh[0]  = *(const ushort4*)(zb + dbase + d0);
    zh[1]  = *(const ushort4*)(zb + dbase + d0 + 4);
    float dtv[8], xsv[8], zv[8];
#pragma unroll
    for (int h = 0; h < 2; ++h) {
        const u16* dp = (const u16*)&dth[h];
        const u16* xp = (const u16*)&xsh[h];
        const u16* zp = (const u16*)&zh[h];
#pragma unroll
        for (int j = 0; j < 4; ++j) {
            dtv[h * 4 + j] = b2f(dp[j]);
            xsv[h * 4 + j] = b2f(xp[j]);
            zv[h * 4 + j]  = b2f(zp[j]);
        }
    }
    float s[8] = {};
#pragma unroll
    for (int n = 0; n < 16; ++n) {
        float4 a0 = *(const float4*)(A + n * DIM + d0);
        float4 a1 = *(const float4*)(A + n * DIM + d0 + 4);
        float pn = Pl[n];
        float av[8] = {a0.x, a0.y, a0.z, a0.w, a1.x, a1.y, a1.z, a1.w};
#pragma unroll
        for (int j = 0; j < 8; ++j) s[j] += pn * __expf(av[j] * dtv[j]);
    }
    ushort4 r0, r1;
    u16* rp0 = (u16*)&r0; u16* rp1 = (u16*)&r1;
#pragma unroll
    for (int j = 0; j < 8; ++j) {
        float y = s[j] * xsv[j];
        float sz = zv[j] * (1.0f / (1.0f + __expf(-zv[j])));
        u16 hv = f2bf(y * sz);
        if (j < 4) rp0[j] = hv; else rp1[j - 4] = hv;
    }
    *(ushort4*)(gated + dbase + d0) = r0;
    *(ushort4*)(gated + dbase + d0 + 4) = r1;
}

// ---------- launch ----------
// PRIMARY layout (needs ws_size >= 101,187,584 B; non-aliased, 5 launches):
//   wb_in  [0, 16.78M)            (-> gated after gemm_wide)
//   xnb    [16.78M, 33.55M)
//   xsb    [33.55M, 50.33M)
//   zb     [50.33M, 67.11M)
//   dtb    [67.11M, 83.89M)
//   wb_dt  [83.89M, 92.54M)  2112x2048 bf16 (rows 2048..2079 = W_B,W_C)
//   wb_out [92.54M, 100.93M)
//   dots   [100.93M, 101.19M)
// FALLBACK = exact round-7 aliased layout (84.15 MB, proven).
extern "C" void kernel_launch(void* const* d_in, const int* in_sizes, int n_in,
                              void* d_out, int out_size, void* d_ws, size_t ws_size,
                              hipStream_t stream) {
    const float* x      = (const float*)d_in[0];
    const float* ln_g   = (const float*)d_in[1];
    const float* ln_b   = (const float*)d_in[2];
    const float* W_in   = (const float*)d_in[3];
    const float* b_in   = (const float*)d_in[4];
    const float* stateA = (const float*)d_in[5];
    const float* W_B    = (const float*)d_in[6];
    const float* b_B    = (const float*)d_in[7];
    const float* W_C    = (const float*)d_in[8];
    const float* b_C    = (const float*)d_in[9];
    const float* W_dt   = (const float*)d_in[10];
    const float* b_dt   = (const float*)d_in[11];
    const float* W_out  = (const float*)d_in[12];
    const float* b_out  = (const float*)d_in[13];

    char* ws = (char*)d_ws;

    if (ws_size >= 101187584ull) {
        // ---- primary: non-aliased, all casts fused ----
        u16* wb_in  = (u16*)(ws);
        u16* gated  = (u16*)(ws);                       // reuse after gemm_wide
        u16* xnb    = (u16*)(ws + 16777216);
        u16* xsb    = (u16*)(ws + 33554432);
        u16* zb     = (u16*)(ws + 50331648);
        u16* dtb    = (u16*)(ws + 67108864);
        u16* wb_dt  = (u16*)(ws + 83886080);
        u16* wb_out = (u16*)(ws + 92536832);
        u16* dotsb  = (u16*)(ws + 100925440);

        castall_kernel<<<20544, 256, 0, stream>>>(W_in, wb_in, x, ln_g, ln_b, xnb,
                                                  W_dt, W_B, W_C, wb_dt,
                                                  W_out, wb_out);
        gemm_wide<<<dim3(32, 32), 256, 0, stream>>>(xnb, wb_in, b_in, xsb, zb, 2048);
        gemm_nw<1><<<dim3(32, 33), 256, 0, stream>>>(xsb, 2048, wb_dt, 2048, b_dt,
                                                     nullptr, dtb, 2048, 2048, dotsb);
        ssm_gate_kernel<<<T_TOK, 256, 0, stream>>>(dtb, xsb, zb, stateA, dotsb,
                                                   b_B, b_C, gated);
        gemm_nw<2><<<dim3(32, 32), 256, 0, stream>>>(gated, 2048, wb_out, 2048, b_out,
                                                     x, (float*)d_out, 2048, 2048, nullptr);
    } else {
        // ---- fallback: exact round-7 schedule (aliased, 84.15 MB) ----
        u16* wb_in  = (u16*)(ws);
        u16* wb_out = (u16*)(ws);
        u16* xnb    = (u16*)(ws + 16777216);
        u16* wb_dt  = (u16*)(ws + 16777216);
        u16* gated  = (u16*)(ws + 16777216);
        u16* xsb    = (u16*)(ws + 33554432);
        u16* zb     = (u16*)(ws + 50331648);
        u16* dtb    = (u16*)(ws + 67108864);
        u16* dotsb  = (u16*)(ws + 83886080);

        castln_kernel<<<12288, 256, 0, stream>>>(W_in, wb_in, x, ln_g, ln_b, xnb);
        gemm_wide<<<dim3(32, 32), 256, 0, stream>>>(xnb, wb_in, b_in, xsb, zb, 2048);
        cast4_kernel<<<8256, 256, 0, stream>>>(
            W_dt, wb_dt, 1048576,
            W_B,  wb_dt + (size_t)2048 * 2048, 8192,
            W_C,  wb_dt + (size_t)2064 * 2048, 8192,
            W_out, wb_out, 1048576);
        gemm_nw<1><<<dim3(32, 33), 256, 0, stream>>>(xsb, 2048, wb_dt, 2048, b_dt,
                                                     nullptr, dtb, 2048, 2048, dotsb);
        ssm_gate_kernel<<<T_TOK, 256, 0, stream>>>(dtb, xsb, zb, stateA, dotsb,
                                                   b_B, b_C, gated);
        gemm_nw<2><<<dim3(32, 32), 256, 0, stream>>>(gated, 2048, wb_out, 2048, b_out,
                                                     x, (float*)d_out, 2048, 2048, nullptr);
    }
}